// Round 1
// baseline (232.904 us; speedup 1.0000x reference)
//
#include <hip/hip_runtime.h>
#include <math.h>

// WaveLM: logits[b,t,v] = sum_{t'<t} g(id[b,t'], v)
// g(u,v) = 2 * sum_{i,j in 1..H} (A_u/i^dec)(A_v/j^dec) * sinc(2*(f_u*i - f_v*j))
// sinc(2d) = sin(2*pi*d)/(2*pi*d), sinc(0)=1
//
// R6: - GT=16 tokens/block == scan segment length; wavelm_g keeps the running
//       prefix in registers, writes the SHIFTED local prefix to out and the
//       segment total to segsum -> wavelm_seg (65.5MB re-read) eliminated.
//     - u-side software prefetch: next token's 28 wave-uniform table values
//       loaded (scalar regs) before current token's ~280-op compute; buffer
//       rotation is uniform -> s_mov (co-issued with VALU).
//     - scan tail: wavelm_bases (tiny 32-wide exclusive scan of segsums) +
//       wavelm_addbase (float4, 8 t/thread, seg==0 blocks skipped).
//     - hot inner loop numerically identical to R5 (packed fp32 via inline
//       asm v_pk_*, batched inversion, guarded rare path).

typedef float v2f __attribute__((ext_vector_type(2)));
typedef float v4f __attribute__((ext_vector_type(4)));

constexpr int cB = 4, cT = 512, cV = 8000, cH = 7;
constexpr int GT = 16;                // tokens per wavelm_g block == seglen
constexpr int NSEG = cT / GT;         // 32 segments
constexpr int NPLANE = 28;            // table planes

__device__ __forceinline__ v2f pk_add(v2f a, v2f b) {
    v2f d; asm("v_pk_add_f32 %0, %1, %2" : "=v"(d) : "v"(a), "v"(b)); return d;
}
__device__ __forceinline__ v2f pk_mul(v2f a, v2f b) {
    v2f d; asm("v_pk_mul_f32 %0, %1, %2" : "=v"(d) : "v"(a), "v"(b)); return d;
}
__device__ __forceinline__ v2f pk_fma(v2f a, v2f b, v2f c) {
    v2f d; asm("v_pk_fma_f32 %0, %1, %2, %3" : "=v"(d) : "v"(a), "v"(b), "v"(c));
    return d;
}

__global__ __launch_bounds__(256) void wavelm_tab(
    const float* __restrict__ freq, const float* __restrict__ amp,
    const float* __restrict__ decay_p, float* __restrict__ tab)
{
    const int v = blockIdx.x * 256 + threadIdx.x;
    if (v >= cV) return;
    const float decay = decay_p[0];
    const float f = freq[v], A = amp[v];
    const float p2 = __builtin_amdgcn_exp2f(-decay);
    const float p3 = __builtin_amdgcn_exp2f(-decay * 1.5849625007f);
    const float p5 = __builtin_amdgcn_exp2f(-decay * 2.3219280949f);
    const float p7 = __builtin_amdgcn_exp2f(-decay * 2.8073549221f);
    const float rp[7] = {1.f, p2, p3, p2*p2, p5, p2*p3, p7};
    const float xr = f - rintf(f);
    const float s1 = __builtin_amdgcn_sinf(xr);
    const float c1 = __builtin_amdgcn_cosf(xr);
    float s = s1, c = c1;
#pragma unroll
    for (int k = 0; k < cH; ++k) {
        if (k) { const float sp = s, cp = c;
                 s = fmaf(sp, c1,  cp * s1);
                 c = fmaf(cp, c1, -(sp * s1)); }
        tab[(size_t)k * cV + v]        = s;
        tab[(size_t)(7 + k) * cV + v]  = c;
        tab[(size_t)(14 + k) * cV + v] = A * rp[k];
        tab[(size_t)(21 + k) * cV + v] = f * (float)(k + 1);
    }
}

__global__ __launch_bounds__(256) void wavelm_g(
    const int* __restrict__ ids, const float* __restrict__ tab,
    float* __restrict__ out, float* __restrict__ segsum, const int segmode)
{
    const int bs  = blockIdx.y;                     // (b, seg) flattened
    const int bt0 = bs * GT;
    const int vh  = blockIdx.x * 256 + threadIdx.x; // v-pair index
    const bool valid = (vh * 2 < cV);
    const int vc = valid ? vh : 0;

    // ---- v-side setup once, amortized over GT tokens ----
    const v2f* tp = (const v2f*)tab;                // plane k: k*(cV/2)+vc
    v2f nb[cH], sBw[cH], cBw[cH];
#pragma unroll
    for (int j = 0; j < cH; ++j) {
        const v2f s = tp[(size_t)j * (cV/2) + vc];
        const v2f c = tp[(size_t)(7 + j) * (cV/2) + vc];
        const v2f w = tp[(size_t)(14 + j) * (cV/2) + vc];
        const v2f a = tp[(size_t)(21 + j) * (cV/2) + vc];
        const v2f ws = w * 0.15915494309189535f;    // w/(2pi)
        sBw[j] = s * ws;
        cBw[j] = c * ws;
        nb[j].x = -a.x;  nb[j].y = -a.y;            // negated: d = aU + nb
    }

    // ---- u-side double buffer (wave-uniform -> scalar regs) ----
    float sA[cH], cA[cH], wA[cH], aU[cH];
    {
        const int id0 = ids[bt0];
#pragma unroll
        for (int i = 0; i < cH; ++i) {
            sA[i] = tab[(size_t)i * cV + id0];
            cA[i] = tab[(size_t)(7 + i) * cV + id0];
            wA[i] = tab[(size_t)(14 + i) * cV + id0];
            aU[i] = tab[(size_t)(21 + i) * cV + id0];
        }
    }

    v2f acc;  acc.x = 0.f;  acc.y = 0.f;            // running segment prefix

    for (int g = 0; g < GT; ++g) {
        // prefetch next token's u-side before this token's compute
        const int gn  = (g + 1 < GT) ? g + 1 : g;
        const int idn = ids[bt0 + gn];
        float sN[cH], cN[cH], wN[cH], aN[cH];
#pragma unroll
        for (int i = 0; i < cH; ++i) {
            sN[i] = tab[(size_t)i * cV + idn];
            cN[i] = tab[(size_t)(7 + i) * cV + idn];
            wN[i] = tab[(size_t)(14 + i) * cV + idn];
            aN[i] = tab[(size_t)(21 + i) * cV + idn];
        }

        float accx = 0.f, accy = 0.f;
        float mn = 3.0e38f, mx = 0.0f;
#pragma unroll
        for (int i = 0; i < cH; ++i) {
            v2f ai;  ai.x = aU[i];  ai.y = aU[i];
            v2f d[cH], p[cH];
#pragma unroll
            for (int j = 0; j < cH; ++j) d[j] = pk_add(ai, nb[j]);
            p[0] = d[0];
#pragma unroll
            for (int j = 1; j < cH; ++j) p[j] = pk_mul(p[j-1], d[j]);
            const float ptot = p[6].x * p[6].y;
            mn = fminf(mn, fminf(fabsf(p[6].x), fabsf(p[6].y)));
            mn = fminf(mn, fabsf(ptot));
            mx = fmaxf(mx, fabsf(ptot));
            const float rt = __builtin_amdgcn_rcpf(ptot);
            v2f r;  r.x = rt * p[6].y;  r.y = rt * p[6].x;   // 1/p6 per comp
            v2f accS = (v2f)0.f, accC = (v2f)0.f;
#pragma unroll
            for (int j = cH - 1; j >= 1; --j) {
                const v2f inv = pk_mul(r, p[j-1]);
                accS = pk_fma(cBw[j], inv, accS);
                accC = pk_fma(sBw[j], inv, accC);
                r = pk_mul(r, d[j]);
            }
            accS = pk_fma(cBw[0], r, accS);
            accC = pk_fma(sBw[0], r, accC);
            // sum_j sn_j*inv_j = sA_i*accS - cA_i*accC  (per component)
            const float tx = fmaf(sA[i], accS.x, -(cA[i] * accC.x));
            const float ty = fmaf(sA[i], accS.y, -(cA[i] * accC.y));
            accx = fmaf(wA[i], tx, accx);
            accy = fmaf(wA[i], ty, accy);
        }

        // rare guarded path: exact-zero d (v==id), underflow, overflow
        if (mn < 1e-37f || mx > 1e37f) {
            accx = 0.f;  accy = 0.f;
#pragma unroll
            for (int i = 0; i < cH; ++i) {
                float ax = 0.f, ay = 0.f;
#pragma unroll
                for (int j = 0; j < cH; ++j) {
                    const v2f w = tp[(size_t)(14 + j) * (cV/2) + vc];
                    const float dx = aU[i] + nb[j].x;
                    const float dy = aU[i] + nb[j].y;
                    const float snx = fmaf(sA[i], cBw[j].x, -(cA[i] * sBw[j].x));
                    const float sny = fmaf(sA[i], cBw[j].y, -(cA[i] * sBw[j].y));
                    float qx = snx * __builtin_amdgcn_rcpf(dx);
                    float qy = sny * __builtin_amdgcn_rcpf(dy);
                    qx = (dx == 0.f) ? w.x : qx;
                    qy = (dy == 0.f) ? w.y : qy;
                    ax += qx;  ay += qy;
                }
                accx = fmaf(wA[i], ax, accx);
                accy = fmaf(wA[i], ay, accy);
            }
        }

        if (valid) {
            v2f res;  res.x = 2.f * accx;  res.y = 2.f * accy;
            const size_t o = (size_t)(bt0 + g) * cV + (size_t)vh * 2;
            // segmode: write shifted local prefix; else raw value
            v2f wv;  wv.x = segmode ? acc.x : res.x;
                     wv.y = segmode ? acc.y : res.y;
            *(v2f*)(out + o) = wv;
            acc = pk_add(acc, res);
        }

        // rotate u-side buffers (uniform -> s_mov, co-issues with VALU)
#pragma unroll
        for (int i = 0; i < cH; ++i) {
            sA[i] = sN[i];  cA[i] = cN[i];  wA[i] = wN[i];  aU[i] = aN[i];
        }
    }

    if (valid && segmode)
        *(v2f*)(segsum + (size_t)bs * cV + (size_t)vh * 2) = acc;
}

// in-place exclusive scan of the NSEG segment sums per (b, v)
__global__ __launch_bounds__(256) void wavelm_bases(float* __restrict__ segsum)
{
    const int g = blockIdx.x * 256 + threadIdx.x;
    if (g >= cB * cV) return;
    const int b = g / cV;
    const int v = g - b * cV;
    float* p = segsum + (size_t)b * NSEG * cV + v;
    float acc = 0.f;
#pragma unroll
    for (int s = 0; s < NSEG; ++s) {
        const float t = p[(size_t)s * cV];
        p[(size_t)s * cV] = acc;
        acc += t;
    }
}

// out[b,t,v] += base(b, t/GT, v); float4 x 8 consecutive t per thread
__global__ __launch_bounds__(256) void wavelm_addbase(
    float* __restrict__ out, const float* __restrict__ bases)
{
    const int btq = blockIdx.y;          // b*(cT/8) + t-octet
    const int b  = btq >> 6;             // cT/8 = 64
    const int t0 = (btq & 63) * 8;
    const int seg = t0 / GT;
    if (seg == 0) return;                // base is zero: out already final
    const int v4 = blockIdx.x * 256 + threadIdx.x;
    if (v4 >= cV / 4) return;

    const v4f base = *(const v4f*)(bases +
        ((size_t)(b * NSEG + seg)) * cV + (size_t)v4 * 4);
    float* p = out + ((size_t)b * cT + t0) * cV + (size_t)v4 * 4;
#pragma unroll
    for (int k = 0; k < 8; ++k) {
        v4f x = *(v4f*)(p + (size_t)k * cV);
        x.x += base.x;  x.y += base.y;  x.z += base.z;  x.w += base.w;
        *(v4f*)(p + (size_t)k * cV) = x;
    }
}

// fallback full-chain scan (ws too small for segsum)
__global__ __launch_bounds__(256) void wavelm_scan(float* __restrict__ out)
{
    const int g = blockIdx.x * blockDim.x + threadIdx.x;
    if (g >= cB * cV) return;
    const int b = g / cV;
    const int v = g - b * cV;
    float* p = out + (size_t)b * cT * cV + v;
    float acc = 0.f;
#pragma unroll 8
    for (int t = 0; t < cT; ++t) {
        const float c = p[(size_t)t * cV];
        p[(size_t)t * cV] = acc;
        acc += c;
    }
}

extern "C" void kernel_launch(void* const* d_in, const int* in_sizes, int n_in,
                              void* d_out, int out_size, void* d_ws, size_t ws_size,
                              hipStream_t stream)
{
    const int*   ids  = (const int*)d_in[0];
    const float* freq = (const float*)d_in[1];
    const float* amp  = (const float*)d_in[2];
    const float* dec  = (const float*)d_in[3];
    float* out = (float*)d_out;
    float* tab = (float*)d_ws;                           // 28*8000*4 = 896 KB
    float* segsum = tab + (size_t)NPLANE * cV;           // 4*32*8000*4 = 4 MB

    const size_t tab_b = (size_t)NPLANE * cV * sizeof(float);
    const size_t seg_b = (size_t)cB * NSEG * cV * sizeof(float);
    const int segmode = (tab_b + seg_b <= ws_size) ? 1 : 0;

    wavelm_tab<<<(cV + 255) / 256, 256, 0, stream>>>(freq, amp, dec, tab);

    dim3 grid((cV / 2 + 255) / 256, cB * cT / GT);       // 16 x 128
    wavelm_g<<<grid, dim3(256), 0, stream>>>(ids, tab, out, segsum, segmode);

    if (segmode) {
        const int nchains = cB * cV;
        wavelm_bases<<<(nchains + 255) / 256, dim3(256), 0, stream>>>(segsum);
        dim3 ab((cV / 4 + 255) / 256, cB * (cT / 8));    // 8 x 256
        wavelm_addbase<<<ab, dim3(256), 0, stream>>>(out, segsum);
    } else {
        const int nchains = cB * cV;
        wavelm_scan<<<(nchains + 255) / 256, dim3(256), 0, stream>>>(out);
    }
}

// Round 2
// 216.370 us; speedup vs baseline: 1.0764x; 1.0764x over previous
//
#include <hip/hip_runtime.h>
#include <math.h>

// WaveLM: logits[b,t,v] = sum_{t'<t} g(id[b,t'], v)
// g(u,v) = 2 * sum_{i,j in 1..H} (A_u/i^dec)(A_v/j^dec) * sinc(2*(f_u*i - f_v*j))
// sinc(2d) = sin(2*pi*d)/(2*pi*d), sinc(0)=1
//
// R7: - GT=16 fused segment scan kept from R6 (wavelm_seg eliminated;
//       wavelm_g writes shifted local prefix + segment total).
//     - R6's u-side value double-buffer REVERTED: 2x28 scalar values blew the
//       SGPR budget (cap 112) and spilled to VGPRs (64->84, occupancy -25%).
//     - Instead: prefetch only the NEXT token id (1 SGPR). idc is known one
//       iteration ahead, so the 28 dependent tab s_loads issue at loop top
//       and the compiler can hoist them into prior compute as SGPRs permit.
//     - hot inner loop numerically identical to R5 (packed fp32 via inline
//       asm v_pk_*, batched inversion, guarded rare path).

typedef float v2f __attribute__((ext_vector_type(2)));
typedef float v4f __attribute__((ext_vector_type(4)));

constexpr int cB = 4, cT = 512, cV = 8000, cH = 7;
constexpr int GT = 16;                // tokens per wavelm_g block == seglen
constexpr int NSEG = cT / GT;         // 32 segments
constexpr int NPLANE = 28;            // table planes

__device__ __forceinline__ v2f pk_add(v2f a, v2f b) {
    v2f d; asm("v_pk_add_f32 %0, %1, %2" : "=v"(d) : "v"(a), "v"(b)); return d;
}
__device__ __forceinline__ v2f pk_mul(v2f a, v2f b) {
    v2f d; asm("v_pk_mul_f32 %0, %1, %2" : "=v"(d) : "v"(a), "v"(b)); return d;
}
__device__ __forceinline__ v2f pk_fma(v2f a, v2f b, v2f c) {
    v2f d; asm("v_pk_fma_f32 %0, %1, %2, %3" : "=v"(d) : "v"(a), "v"(b), "v"(c));
    return d;
}

__global__ __launch_bounds__(256) void wavelm_tab(
    const float* __restrict__ freq, const float* __restrict__ amp,
    const float* __restrict__ decay_p, float* __restrict__ tab)
{
    const int v = blockIdx.x * 256 + threadIdx.x;
    if (v >= cV) return;
    const float decay = decay_p[0];
    const float f = freq[v], A = amp[v];
    const float p2 = __builtin_amdgcn_exp2f(-decay);
    const float p3 = __builtin_amdgcn_exp2f(-decay * 1.5849625007f);
    const float p5 = __builtin_amdgcn_exp2f(-decay * 2.3219280949f);
    const float p7 = __builtin_amdgcn_exp2f(-decay * 2.8073549221f);
    const float rp[7] = {1.f, p2, p3, p2*p2, p5, p2*p3, p7};
    const float xr = f - rintf(f);
    const float s1 = __builtin_amdgcn_sinf(xr);
    const float c1 = __builtin_amdgcn_cosf(xr);
    float s = s1, c = c1;
#pragma unroll
    for (int k = 0; k < cH; ++k) {
        if (k) { const float sp = s, cp = c;
                 s = fmaf(sp, c1,  cp * s1);
                 c = fmaf(cp, c1, -(sp * s1)); }
        tab[(size_t)k * cV + v]        = s;
        tab[(size_t)(7 + k) * cV + v]  = c;
        tab[(size_t)(14 + k) * cV + v] = A * rp[k];
        tab[(size_t)(21 + k) * cV + v] = f * (float)(k + 1);
    }
}

__global__ __launch_bounds__(256) void wavelm_g(
    const int* __restrict__ ids, const float* __restrict__ tab,
    float* __restrict__ out, float* __restrict__ segsum, const int segmode)
{
    const int bs  = blockIdx.y;                     // (b, seg) flattened
    const int bt0 = bs * GT;
    const int vh  = blockIdx.x * 256 + threadIdx.x; // v-pair index
    const bool valid = (vh * 2 < cV);
    const int vc = valid ? vh : 0;

    // ---- v-side setup once, amortized over GT tokens ----
    const v2f* tp = (const v2f*)tab;                // plane k: k*(cV/2)+vc
    v2f nb[cH], sBw[cH], cBw[cH];
#pragma unroll
    for (int j = 0; j < cH; ++j) {
        const v2f s = tp[(size_t)j * (cV/2) + vc];
        const v2f c = tp[(size_t)(7 + j) * (cV/2) + vc];
        const v2f w = tp[(size_t)(14 + j) * (cV/2) + vc];
        const v2f a = tp[(size_t)(21 + j) * (cV/2) + vc];
        const v2f ws = w * 0.15915494309189535f;    // w/(2pi)
        sBw[j] = s * ws;
        cBw[j] = c * ws;
        nb[j].x = -a.x;  nb[j].y = -a.y;            // negated: d = aU + nb
    }

    v2f acc;  acc.x = 0.f;  acc.y = 0.f;            // running segment prefix

    int idc = ids[bt0];                             // current token id (SGPR)
    for (int g = 0; g < GT; ++g) {
        // prefetch only the NEXT id (1 SGPR); breaks the id->tab serial chain
        const int idn = (g + 1 < GT) ? ids[bt0 + g + 1] : idc;

        // u-side: 28 wave-uniform scalar loads, address known at loop top
        float sA[cH], cA[cH], wA[cH], aU[cH];
#pragma unroll
        for (int i = 0; i < cH; ++i) {
            sA[i] = tab[(size_t)i * cV + idc];
            cA[i] = tab[(size_t)(7 + i) * cV + idc];
            wA[i] = tab[(size_t)(14 + i) * cV + idc];
            aU[i] = tab[(size_t)(21 + i) * cV + idc];
        }

        float accx = 0.f, accy = 0.f;
        float mn = 3.0e38f, mx = 0.0f;
#pragma unroll
        for (int i = 0; i < cH; ++i) {
            v2f ai;  ai.x = aU[i];  ai.y = aU[i];
            v2f d[cH], p[cH];
#pragma unroll
            for (int j = 0; j < cH; ++j) d[j] = pk_add(ai, nb[j]);
            p[0] = d[0];
#pragma unroll
            for (int j = 1; j < cH; ++j) p[j] = pk_mul(p[j-1], d[j]);
            const float ptot = p[6].x * p[6].y;
            mn = fminf(mn, fminf(fabsf(p[6].x), fabsf(p[6].y)));
            mn = fminf(mn, fabsf(ptot));
            mx = fmaxf(mx, fabsf(ptot));
            const float rt = __builtin_amdgcn_rcpf(ptot);
            v2f r;  r.x = rt * p[6].y;  r.y = rt * p[6].x;   // 1/p6 per comp
            v2f accS = (v2f)0.f, accC = (v2f)0.f;
#pragma unroll
            for (int j = cH - 1; j >= 1; --j) {
                const v2f inv = pk_mul(r, p[j-1]);
                accS = pk_fma(cBw[j], inv, accS);
                accC = pk_fma(sBw[j], inv, accC);
                r = pk_mul(r, d[j]);
            }
            accS = pk_fma(cBw[0], r, accS);
            accC = pk_fma(sBw[0], r, accC);
            // sum_j sn_j*inv_j = sA_i*accS - cA_i*accC  (per component)
            const float tx = fmaf(sA[i], accS.x, -(cA[i] * accC.x));
            const float ty = fmaf(sA[i], accS.y, -(cA[i] * accC.y));
            accx = fmaf(wA[i], tx, accx);
            accy = fmaf(wA[i], ty, accy);
        }

        // rare guarded path: exact-zero d (v==id), underflow, overflow
        if (mn < 1e-37f || mx > 1e37f) {
            accx = 0.f;  accy = 0.f;
#pragma unroll
            for (int i = 0; i < cH; ++i) {
                float ax = 0.f, ay = 0.f;
#pragma unroll
                for (int j = 0; j < cH; ++j) {
                    const v2f w = tp[(size_t)(14 + j) * (cV/2) + vc];
                    const float dx = aU[i] + nb[j].x;
                    const float dy = aU[i] + nb[j].y;
                    const float snx = fmaf(sA[i], cBw[j].x, -(cA[i] * sBw[j].x));
                    const float sny = fmaf(sA[i], cBw[j].y, -(cA[i] * sBw[j].y));
                    float qx = snx * __builtin_amdgcn_rcpf(dx);
                    float qy = sny * __builtin_amdgcn_rcpf(dy);
                    qx = (dx == 0.f) ? w.x : qx;
                    qy = (dy == 0.f) ? w.y : qy;
                    ax += qx;  ay += qy;
                }
                accx = fmaf(wA[i], ax, accx);
                accy = fmaf(wA[i], ay, accy);
            }
        }

        if (valid) {
            v2f res;  res.x = 2.f * accx;  res.y = 2.f * accy;
            const size_t o = (size_t)(bt0 + g) * cV + (size_t)vh * 2;
            // segmode: write shifted local prefix; else raw value
            v2f wv;  wv.x = segmode ? acc.x : res.x;
                     wv.y = segmode ? acc.y : res.y;
            *(v2f*)(out + o) = wv;
            acc = pk_add(acc, res);
        }

        idc = idn;
    }

    if (valid && segmode)
        *(v2f*)(segsum + (size_t)bs * cV + (size_t)vh * 2) = acc;
}

// in-place exclusive scan of the NSEG segment sums per (b, v)
__global__ __launch_bounds__(256) void wavelm_bases(float* __restrict__ segsum)
{
    const int g = blockIdx.x * 256 + threadIdx.x;
    if (g >= cB * cV) return;
    const int b = g / cV;
    const int v = g - b * cV;
    float* p = segsum + (size_t)b * NSEG * cV + v;
    float acc = 0.f;
#pragma unroll
    for (int s = 0; s < NSEG; ++s) {
        const float t = p[(size_t)s * cV];
        p[(size_t)s * cV] = acc;
        acc += t;
    }
}

// out[b,t,v] += base(b, t/GT, v); float4 x 8 consecutive t per thread
__global__ __launch_bounds__(256) void wavelm_addbase(
    float* __restrict__ out, const float* __restrict__ bases)
{
    const int btq = blockIdx.y;          // b*(cT/8) + t-octet
    const int b  = btq >> 6;             // cT/8 = 64
    const int t0 = (btq & 63) * 8;
    const int seg = t0 / GT;
    if (seg == 0) return;                // base is zero: out already final
    const int v4 = blockIdx.x * 256 + threadIdx.x;
    if (v4 >= cV / 4) return;

    const v4f base = *(const v4f*)(bases +
        ((size_t)(b * NSEG + seg)) * cV + (size_t)v4 * 4);
    float* p = out + ((size_t)b * cT + t0) * cV + (size_t)v4 * 4;
#pragma unroll
    for (int k = 0; k < 8; ++k) {
        v4f x = *(v4f*)(p + (size_t)k * cV);
        x.x += base.x;  x.y += base.y;  x.z += base.z;  x.w += base.w;
        *(v4f*)(p + (size_t)k * cV) = x;
    }
}

// fallback full-chain scan (ws too small for segsum)
__global__ __launch_bounds__(256) void wavelm_scan(float* __restrict__ out)
{
    const int g = blockIdx.x * blockDim.x + threadIdx.x;
    if (g >= cB * cV) return;
    const int b = g / cV;
    const int v = g - b * cV;
    float* p = out + (size_t)b * cT * cV + v;
    float acc = 0.f;
#pragma unroll 8
    for (int t = 0; t < cT; ++t) {
        const float c = p[(size_t)t * cV];
        p[(size_t)t * cV] = acc;
        acc += c;
    }
}

extern "C" void kernel_launch(void* const* d_in, const int* in_sizes, int n_in,
                              void* d_out, int out_size, void* d_ws, size_t ws_size,
                              hipStream_t stream)
{
    const int*   ids  = (const int*)d_in[0];
    const float* freq = (const float*)d_in[1];
    const float* amp  = (const float*)d_in[2];
    const float* dec  = (const float*)d_in[3];
    float* out = (float*)d_out;
    float* tab = (float*)d_ws;                           // 28*8000*4 = 896 KB
    float* segsum = tab + (size_t)NPLANE * cV;           // 4*32*8000*4 = 4 MB

    const size_t tab_b = (size_t)NPLANE * cV * sizeof(float);
    const size_t seg_b = (size_t)cB * NSEG * cV * sizeof(float);
    const int segmode = (tab_b + seg_b <= ws_size) ? 1 : 0;

    wavelm_tab<<<(cV + 255) / 256, 256, 0, stream>>>(freq, amp, dec, tab);

    dim3 grid((cV / 2 + 255) / 256, cB * cT / GT);       // 16 x 128
    wavelm_g<<<grid, dim3(256), 0, stream>>>(ids, tab, out, segsum, segmode);

    if (segmode) {
        const int nchains = cB * cV;
        wavelm_bases<<<(nchains + 255) / 256, dim3(256), 0, stream>>>(segsum);
        dim3 ab((cV / 4 + 255) / 256, cB * (cT / 8));    // 8 x 256
        wavelm_addbase<<<ab, dim3(256), 0, stream>>>(out, segsum);
    } else {
        const int nchains = cB * cV;
        wavelm_scan<<<(nchains + 255) / 256, dim3(256), 0, stream>>>(out);
    }
}